// Round 1
// baseline (123.324 us; speedup 1.0000x reference)
//
#include <hip/hip_runtime.h>
#include <hip/hip_bf16.h>

// Integrate-and-Fire over T=32 timesteps.
// x: [T, B, N] f32, contiguous. Each thread owns 4 consecutive elements of the
// flattened [B*N] plane and walks t with stride BN (coalesced each step).
// mem += x_t; spike = (mem - 1.0 > 0); mem = 0 where spiked.

#define THRESHOLD 1.0f

__global__ __launch_bounds__(256) void if_kernel(const float4* __restrict__ x,
                                                 float4* __restrict__ out,
                                                 int bn4, int T) {
    int i = blockIdx.x * blockDim.x + threadIdx.x;
    if (i >= bn4) return;

    float4 mem = make_float4(0.f, 0.f, 0.f, 0.f);
    size_t idx = (size_t)i;
    #pragma unroll
    for (int t = 0; t < 32; ++t) {
        if (t >= T) break;
        float4 xv = x[idx];
        mem.x += xv.x; mem.y += xv.y; mem.z += xv.z; mem.w += xv.w;
        float sx = (mem.x - THRESHOLD > 0.f) ? 1.f : 0.f;
        float sy = (mem.y - THRESHOLD > 0.f) ? 1.f : 0.f;
        float sz = (mem.z - THRESHOLD > 0.f) ? 1.f : 0.f;
        float sw = (mem.w - THRESHOLD > 0.f) ? 1.f : 0.f;
        mem.x = (sx > 0.5f) ? 0.f : mem.x;
        mem.y = (sy > 0.5f) ? 0.f : mem.y;
        mem.z = (sz > 0.5f) ? 0.f : mem.z;
        mem.w = (sw > 0.5f) ? 0.f : mem.w;
        out[idx] = make_float4(sx, sy, sz, sw);
        idx += (size_t)bn4;
    }
}

extern "C" void kernel_launch(void* const* d_in, const int* in_sizes, int n_in,
                              void* d_out, int out_size, void* d_ws, size_t ws_size,
                              hipStream_t stream) {
    const float* x = (const float*)d_in[0];
    float* out = (float*)d_out;

    const int T = 32;
    const int total = in_sizes[0];        // T * B * N
    const int bn = total / T;             // B * N = 2097152
    const int bn4 = bn / 4;               // 524288 float4 columns

    const int block = 256;
    const int grid = (bn4 + block - 1) / block;  // 2048

    if_kernel<<<grid, block, 0, stream>>>((const float4*)x, (float4*)out, bn4, T);
}

// Round 2
// 120.224 us; speedup vs baseline: 1.0258x; 1.0258x over previous
//
#include <hip/hip_runtime.h>
#include <hip/hip_bf16.h>

// Integrate-and-Fire over T=32 timesteps, x: [T, B, N] f32.
// One thread owns 4 consecutive elements of the [B*N] plane; walks t with
// stride BN/4 float4s. Software-pipelined in chunks of 8 timesteps so 8-16
// 16B loads are in flight per thread at all times. Nontemporal hints: both
// streams are read-once/write-once and together (512 MiB) exceed L3 (256 MiB).

#define THRESHOLD 1.0f

typedef float f32x4 __attribute__((ext_vector_type(4)));

__global__ __launch_bounds__(256) void if_kernel(const f32x4* __restrict__ x,
                                                 f32x4* __restrict__ out,
                                                 int bn4) {
    const size_t i = (size_t)blockIdx.x * blockDim.x + threadIdx.x;
    if (i >= (size_t)bn4) return;

    const size_t stride = (size_t)bn4;
    const f32x4* xp = x + i;
    f32x4* op = out + i;

    f32x4 mem;
    mem.x = 0.f; mem.y = 0.f; mem.z = 0.f; mem.w = 0.f;

    f32x4 cur[8], nxt[8];

    // Prologue: first chunk of 8 timesteps.
    #pragma unroll
    for (int j = 0; j < 8; ++j)
        cur[j] = __builtin_nontemporal_load(xp + (size_t)j * stride);

    #pragma unroll
    for (int tc = 0; tc < 4; ++tc) {
        // Prefetch next chunk before computing current one.
        if (tc < 3) {
            #pragma unroll
            for (int j = 0; j < 8; ++j)
                nxt[j] = __builtin_nontemporal_load(
                    xp + (size_t)((tc + 1) * 8 + j) * stride);
        }

        #pragma unroll
        for (int j = 0; j < 8; ++j) {
            f32x4 spk;
            mem.x += cur[j].x;
            mem.y += cur[j].y;
            mem.z += cur[j].z;
            mem.w += cur[j].w;
            spk.x = (mem.x - THRESHOLD > 0.f) ? 1.f : 0.f;
            spk.y = (mem.y - THRESHOLD > 0.f) ? 1.f : 0.f;
            spk.z = (mem.z - THRESHOLD > 0.f) ? 1.f : 0.f;
            spk.w = (mem.w - THRESHOLD > 0.f) ? 1.f : 0.f;
            mem.x = (spk.x > 0.5f) ? 0.f : mem.x;
            mem.y = (spk.y > 0.5f) ? 0.f : mem.y;
            mem.z = (spk.z > 0.5f) ? 0.f : mem.z;
            mem.w = (spk.w > 0.5f) ? 0.f : mem.w;
            __builtin_nontemporal_store(spk, op + (size_t)(tc * 8 + j) * stride);
        }

        #pragma unroll
        for (int j = 0; j < 8; ++j) cur[j] = nxt[j];
    }
}

extern "C" void kernel_launch(void* const* d_in, const int* in_sizes, int n_in,
                              void* d_out, int out_size, void* d_ws, size_t ws_size,
                              hipStream_t stream) {
    const float* x = (const float*)d_in[0];
    float* out = (float*)d_out;

    const int T = 32;
    const int total = in_sizes[0];        // T * B * N
    const int bn = total / T;             // B * N = 2097152
    const int bn4 = bn / 4;               // 524288 float4 columns

    const int block = 256;
    const int grid = (bn4 + block - 1) / block;  // 2048

    if_kernel<<<grid, block, 0, stream>>>((const f32x4*)x, (f32x4*)out, bn4);
}